// Round 8
// baseline (210.296 us; speedup 1.0000x reference)
//
#include <hip/hip_runtime.h>

#define SS 730
#define GG 4000
#define GH 2000        // half of GG: each thread owns cells g and g+GH
#define GHPAD 2048     // pad half-range to full waves; no wave mixes models
#define LENF 15
#define PD 10          // prefetch depth (steps); 730 % 10 == 0
#define TT 10          // route time-tile; 730 % 10 == 0
#define QN ((size_t)SS * GG)
#define QNI ((int)(SS * GG))

// ---------------------------------------------------------------------------
// Scan kernel: one thread per (cell-pair, multiplier m, model), SPLIT by
// model/multiplier across waves. inst = tid/GHPAD: 0,1 -> HBV (m=inst&1);
// 2,3 -> EXP (m=inst&1). Each thread runs TWO cells (g, g+GH) of the SAME
// model: two homogeneous independent dependent chains in one thread fill
// each other's latency bubbles (round-4's heterogeneous fusion serialized;
// homogeneous worst-case is neutral, interleave is up to ~1.6x).
// Round-7 algebraic chain trims retained.
// ---------------------------------------------------------------------------
template<bool STORE4>
__global__ __launch_bounds__(64, 1) void hydro_scan(const float* __restrict__ x,
                                                    const float* __restrict__ raw,
                                                    float* __restrict__ qsim) {
    int tid = blockIdx.x * 64 + threadIdx.x;
    int gh = tid % GHPAD;
    int inst = tid / GHPAD;
    if (gh >= GH) return;
    int m = inst & 1;

    // per-pair pointers / offsets
    const float* pr0 = raw + (size_t)gh * 38 + m;
    const float* pr1 = raw + (size_t)(gh + GH) * 38 + m;
    int xoff[2] = { gh * 3, (gh + GH) * 3 };
    int qoff[2] = { gh + (STORE4 ? inst * QNI : 0),
                    gh + GH + (STORE4 ? inst * QNI : 0) };

    // prefetch pipeline: steps 0..PD-1, both cells
    float pb[2][PD], tb[2][PD], eb[2][PD];
#pragma unroll
    for (int j = 0; j < PD; ++j) {
#pragma unroll
        for (int u = 0; u < 2; ++u) {
            pb[u][j] = x[xoff[u]]; tb[u][j] = x[xoff[u] + 1]; eb[u][j] = x[xoff[u] + 2];
            xoff[u] += 3 * GG;
        }
    }

    if (inst < 2) {
        // ---- HBV parameters (descale + derived constants), both cells ----
        float beta[2], invfc[2], invlpfc[2], ncfrcf[2], cfmax[2], cwh[2],
              tt[2], perc[2], omk0[2], k0uzl[2], omk1[2], k2[2], fc[2];
        float sp[2], mw[2], sm[2], suz[2], slz[2];
#pragma unroll
        for (int u = 0; u < 2; ++u) {
            const float* pr = u ? pr1 : pr0;
            beta[u]  = 1.0f   + pr[0]  * 5.0f;
            fc[u]    = 50.0f  + pr[2]  * 950.0f;
            float k0 = 0.05f  + pr[4]  * 0.85f;
            float k1 = 0.01f  + pr[6]  * 0.49f;
            k2[u]    = 0.001f + pr[8]  * 0.199f;
            float lp = 0.2f   + pr[10] * 0.8f;
            perc[u]  =          pr[12] * 10.0f;
            float uzl =         pr[14] * 100.0f;
            tt[u]    = -2.5f  + pr[16] * 5.0f;
            cfmax[u] = 0.5f   + pr[18] * 9.5f;
            float cfr =         pr[20] * 0.1f;
            cwh[u]   =          pr[22] * 0.2f;
            invfc[u]   = 1.0f / fc[u];
            invlpfc[u] = 1.0f / (lp * fc[u]);
            ncfrcf[u]  = -(cfr * cfmax[u]);
            omk0[u]    = 1.0f - k0;
            k0uzl[u]   = k0 * uzl;
            omk1[u]    = 1.0f - k1;
            sp[u] = 1e-5f; mw[u] = 1e-5f; sm[u] = 0.5f * fc[u];
            suz[u] = 1e-5f; slz[u] = 1e-5f;
        }

        auto step = [&](int j, bool pre) {
#pragma unroll
            for (int u = 0; u < 2; ++u) {
                float p = pb[u][j], tc = tb[u][j], pet = eb[u][j];
                if (pre) {
                    pb[u][j] = x[xoff[u]]; tb[u][j] = x[xoff[u] + 1]; eb[u][j] = x[xoff[u] + 2];
                    xoff[u] += 3 * GG;
                }
                // off-chain (forcing-only) terms
                float dt   = tc - tt[u];
                float msn  = fmaxf(cfmax[u] * dt, 0.0f);
                float mrf  = fmaxf(ncfrcf[u] * dt, 0.0f);
                float rain = (dt >= 0.0f) ? p : 0.0f;
                float snow = p - rain;
                float etk  = fmaf(-invlpfc[u], pet, 1.0f);
                // long pole: sw from previous-step sm
                float sw   = exp2f(beta[u] * __log2f(sm[u] * invfc[u]));
                float omsw = 1.0f - sw;
                // snow / melt-water chains
                float sp1  = sp[u] + snow;
                float melt = fminf(msn, sp1);
                float mw2  = mw[u] + melt;
                float sp2  = sp1 - melt;
                float refr = fminf(mrf, mw2);
                float mw3  = mw2 - refr;
                sp[u] = sp2 + refr;
                float mw4  = fminf(mw3, cwh[u] * sp[u]);
                float tosoil = mw3 - mw4;
                mw[u] = mw4;
                // soil moisture
                float rt    = rain + tosoil;
                float sm1   = fmaf(rt, omsw, sm[u]);
                float rech  = rt * sw;
                float excess = fmaxf(sm1 - fc[u], 0.0f);
                float sm2   = fminf(sm1, fc[u]);
                sm[u] = fmaxf(fmaxf(sm2 * etk, sm2 - pet), 1e-5f);
                // upper / lower zones
                float suz1 = suz[u] + rech + excess;
                float suz2 = fmaxf(suz1 - perc[u], 0.0f);
                float pa   = suz1 - suz2;
                float suz3 = fminf(suz2, fmaf(suz2, omk0[u], k0uzl[u]));
                float suzn = omk1[u] * suz3;
                float q01  = suz2 - suzn;
                suz[u] = suzn;
                float slz1 = slz[u] + pa;
                float q2   = k2[u] * slz1;
                slz[u] = slz1 - q2;
                float q = q01 + q2;
                if (STORE4) qsim[qoff[u]] = q; else atomicAdd(&qsim[qoff[u]], 0.25f * q);
                qoff[u] += GG;
            }
        };

        for (int c = 0; c < SS / PD - 1; ++c) {
#pragma unroll
            for (int j = 0; j < PD; ++j) step(j, true);
        }
#pragma unroll
        for (int j = 0; j < PD; ++j) step(j, false);   // peeled last chunk
    } else {
        // ---- EXP-HYDRO parameters (descale + derived), both cells ----
        float fl[2], c0[2], smax[2], invsmax[2], df[2], tmax[2], tmin[2];
        float s0[2], s1[2];
#pragma unroll
        for (int u = 0; u < 2; ++u) {
            const float* pe = (u ? pr1 : pr0) + 24;
            float f    =           pe[0]  * 0.1f;
            smax[u]    = 100.0f  + pe[2]  * 1400.0f;
            float qmax = 10.0f   + pe[4]  * 40.0f;
            df[u]      =           pe[6]  * 5.0f;
            tmax[u]    =           pe[8]  * 3.0f;
            tmin[u]    = -3.0f   + pe[10] * 3.0f;
            invsmax[u] = 1.0f / smax[u];
            fl[u] = f * 1.44269504f;
            c0[u] = __log2f(qmax) - fl[u] * smax[u];
            s0[u] = 1e-5f; s1[u] = 0.5f * smax[u];
        }

        auto step = [&](int j, bool pre) {
#pragma unroll
            for (int u = 0; u < 2; ++u) {
                float p = pb[u][j], tc = tb[u][j], pet = eb[u][j];
                if (pre) {
                    pb[u][j] = x[xoff[u]]; tb[u][j] = x[xoff[u] + 1]; eb[u][j] = x[xoff[u] + 2];
                    xoff[u] += 3 * GG;
                }
                float mdf = df[u] * fmaxf(tc - tmax[u], 0.0f);
                float ps  = (tc <= tmin[u]) ? p : 0.0f;
                float prr = p - ps;
                float etk = fmaxf(fmaf(-invsmax[u], pet, 1.0f), 0.0f);
                float mlt = fminf(s0[u], mdf);
                s0[u] = fmaxf(s0[u] - mdf, 0.0f) + ps;
                float s1a = s1[u] + prr + mlt;
                float qspill = fmaxf(s1a - smax[u], 0.0f);
                float s1b = fminf(s1a, smax[u]);
                float s1c = s1b * etk;
                float qb  = fminf(exp2f(fmaf(fl[u], s1c, c0[u])), s1c);
                s1[u] = s1c - qb;
                float q = qspill + qb;
                if (STORE4) qsim[qoff[u]] = q; else atomicAdd(&qsim[qoff[u]], 0.25f * q);
                qoff[u] += GG;
            }
        };

        for (int c = 0; c < SS / PD - 1; ++c) {
#pragma unroll
            for (int j = 0; j < PD; ++j) step(j, true);
        }
#pragma unroll
        for (int j = 0; j < PD; ++j) step(j, false);
    }
}

// ---------------------------------------------------------------------------
// UH weights: one thread per g, 15 normalized gamma-UH weights once (0.25
// folded). gammaln cancels: w[k] ∝ exp((aa-1)ln(k+.5)-(k+.5)/th).
// ---------------------------------------------------------------------------
__global__ __launch_bounds__(256) void uh_weights(const float* __restrict__ raw,
                                                  float* __restrict__ wbuf) {
    int g = blockIdx.x * 256 + threadIdx.x;
    if (g >= GG) return;
    float a = raw[(size_t)g * 38 + 36] * 2.9f;
    float b = raw[(size_t)g * 38 + 37] * 6.5f;
    float aa = fmaxf(a, 0.0f) + 0.1f;
    float th = fmaxf(b, 0.0f) + 0.5f;
    float am1 = aa - 1.0f;
    float invth = 1.0f / th;

    const float logt[LENF] = {
        -0.69314718f, 0.40546511f, 0.91629073f, 1.25276297f, 1.50407740f,
         1.70474809f, 1.87180218f, 2.01490302f, 2.14006616f, 2.25129180f,
         2.35137526f, 2.44234704f, 2.52572864f, 2.60268969f, 2.67414865f };

    float w[LENF];
    float s = 0.0f;
#pragma unroll
    for (int k = 0; k < LENF; ++k) {
        float tk = (float)k + 0.5f;
        w[k] = expf(am1 * logt[k] - tk * invth);
        s += w[k];
    }
    float scale = 0.25f / s;
#pragma unroll
    for (int k = 0; k < LENF; ++k)
        wbuf[(size_t)k * GG + g] = w[k] * scale;
}

// ---------------------------------------------------------------------------
// Routing kernel, t-tiled: each thread owns one g and TT consecutive t's.
// WPRE: weights preloaded from wbuf (scale folded). NB = #qsim slices summed.
// ---------------------------------------------------------------------------
template<int NB, bool WPRE>
__global__ __launch_bounds__(256) void hydro_route(const float* __restrict__ qsim,
                                                   const float* __restrict__ raw,
                                                   const float* __restrict__ wbuf,
                                                   float* __restrict__ out) {
    int idx = blockIdx.x * 256 + threadIdx.x;
    if (idx >= GG * (SS / TT)) return;
    int g = idx % GG;          // g fast -> coalesced
    int c = idx / GG;
    int t0 = c * TT;

    float w[LENF];
    float scale;
    if (WPRE) {
#pragma unroll
        for (int k = 0; k < LENF; ++k)
            w[k] = wbuf[(size_t)k * GG + g];
        scale = 1.0f;
    } else {
        float a = raw[(size_t)g * 38 + 36] * 2.9f;
        float b = raw[(size_t)g * 38 + 37] * 6.5f;
        float aa = fmaxf(a, 0.0f) + 0.1f;
        float th = fmaxf(b, 0.0f) + 0.5f;
        float am1 = aa - 1.0f;
        float invth = 1.0f / th;
        const float logt[LENF] = {
            -0.69314718f, 0.40546511f, 0.91629073f, 1.25276297f, 1.50407740f,
             1.70474809f, 1.87180218f, 2.01490302f, 2.14006616f, 2.25129180f,
             2.35137526f, 2.44234704f, 2.52572864f, 2.60268969f, 2.67414865f };
        float s = 0.0f;
#pragma unroll
        for (int k = 0; k < LENF; ++k) {
            float tk = (float)k + 0.5f;
            w[k] = expf(am1 * logt[k] - tk * invth);
            s += w[k];
        }
        scale = (NB == 4 ? 0.25f : 1.0f) / s;
    }

    // load qsim[t0-14 .. t0+TT-1] (zeros before t=0), summing NB slices
    float v[TT + LENF - 1];
#pragma unroll
    for (int i = 0; i < TT + LENF - 1; ++i) {
        int tp = t0 - (LENF - 1) + i;
        float sv = 0.0f;
        if (tp >= 0) {
            const float* qb = qsim + (size_t)tp * GG + g;
            sv = qb[0];
            if (NB == 4) sv += qb[QN] + qb[2 * QN] + qb[3 * QN];
        }
        v[i] = sv;
    }
#pragma unroll
    for (int j = 0; j < TT; ++j) {
        float acc = 0.0f;
#pragma unroll
        for (int k = 0; k < LENF; ++k)
            acc += w[k] * v[j + (LENF - 1) - k];
        out[(size_t)(t0 + j) * GG + g] = (WPRE ? acc : acc * scale);
    }
}

// ---------------------------------------------------------------------------
extern "C" void kernel_launch(void* const* d_in, const int* in_sizes, int n_in,
                              void* d_out, int out_size, void* d_ws, size_t ws_size,
                              hipStream_t stream) {
    const float* x   = (const float*)d_in[0];   // (730, 4000, 3) f32
    const float* raw = (const float*)d_in[1];   // (4000, 38) f32
    float* out  = (float*)d_out;                // (730, 4000) f32
    float* qsim = (float*)d_ws;

    const size_t slices4 = 4 * QN * sizeof(float);
    const size_t wbytes  = (size_t)LENF * GG * sizeof(float);
    int rblocks = (GG * (SS / TT) + 255) / 256;
    int sblocks = (4 * GHPAD) / 64;

    if (ws_size >= slices4 + wbytes) {
        float* wbuf = qsim + 4 * QN;
        hydro_scan<true><<<sblocks, 64, 0, stream>>>(x, raw, qsim);
        uh_weights<<<(GG + 255) / 256, 256, 0, stream>>>(raw, wbuf);
        hydro_route<4, true><<<rblocks, 256, 0, stream>>>(qsim, raw, wbuf, out);
    } else if (ws_size >= slices4) {
        hydro_scan<true><<<sblocks, 64, 0, stream>>>(x, raw, qsim);
        hydro_route<4, false><<<rblocks, 256, 0, stream>>>(qsim, raw, nullptr, out);
    } else {
        hipMemsetAsync(qsim, 0, QN * sizeof(float), stream);
        hydro_scan<false><<<sblocks, 64, 0, stream>>>(x, raw, qsim);
        hydro_route<1, false><<<rblocks, 256, 0, stream>>>(qsim, raw, nullptr, out);
    }
}

// Round 9
// 113.599 us; speedup vs baseline: 1.8512x; 1.8512x over previous
//
#include <hip/hip_runtime.h>

#define SS 730
#define GG 4000
#define LENF 15
#define PD 10          // prefetch depth (steps); 730 % 10 == 0
#define GPAD 4032      // 63 waves per instance -> no wave mixes models
#define TT 10          // route time-tile; 730 % 10 == 0
#define QN ((size_t)SS * GG)
#define QNI ((int)(SS * GG))
#define QS1I ((int)((SS + 1) * GG))          // slice stride incl. t=-1 pad row
#define QS1 ((size_t)(SS + 1) * GG)

// ---------------------------------------------------------------------------
// Scan kernel: one thread per (cell g, multiplier m, model), SPLIT topology
// (round-7 base, the best so far). inst = tid/GPAD: 0,1 -> HBV; 2,3 -> EXP.
// Round-9 additions (manual cross-step software pipelining; with 1 wave/SIMD
// and in-order issue, any op that stalls blocks the whole wave, so:)
//   * deferred store: q[t] is stored at the TOP of step t+1, when its long
//     dependency chain has already resolved. Each slice has a -1 pad row
//     (stride (SS+1)*GG) absorbing the first garbage store.
//   * pipelined sw: exp2(beta*log2(sm/fc)) for step t+1 is issued right
//     after sm[t+1] is available in step t, overlapping its latency with
//     the suz/slz tail and the next step's snow chain.
// ---------------------------------------------------------------------------
template<bool STORE4>
__global__ __launch_bounds__(64, 1) void hydro_scan(const float* __restrict__ x,
                                                    const float* __restrict__ raw,
                                                    float* __restrict__ qsim) {
    int tid = blockIdx.x * 64 + threadIdx.x;
    int g = tid % GPAD;
    int inst = tid / GPAD;
    if (g >= GG) return;
    int m = inst & 1;
    const float* pr = raw + (size_t)g * 38 + m;   // pr[2*i] = raw[g, i*2+m]

    int xoff = g * 3;
    // STORE4: qoff starts at the pad row (t=-1) of this instance's slice.
    int qoff = STORE4 ? (inst * QS1I + g) : g;

    // prefetch pipeline: steps 0..PD-1
    float pb[PD], tb[PD], eb[PD];
#pragma unroll
    for (int j = 0; j < PD; ++j) {
        pb[j] = x[xoff]; tb[j] = x[xoff + 1]; eb[j] = x[xoff + 2];
        xoff += 3 * GG;
    }

    if (inst < 2) {
        // ---- HBV parameters (descale + derived constants) ----
        float beta  = 1.0f   + pr[0]  * 5.0f;
        float fc    = 50.0f  + pr[2]  * 950.0f;
        float k0    = 0.05f  + pr[4]  * 0.85f;
        float k1    = 0.01f  + pr[6]  * 0.49f;
        float k2    = 0.001f + pr[8]  * 0.199f;
        float lp    = 0.2f   + pr[10] * 0.8f;
        float perc  =          pr[12] * 10.0f;
        float uzl   =          pr[14] * 100.0f;
        float tt    = -2.5f  + pr[16] * 5.0f;
        float cfmax = 0.5f   + pr[18] * 9.5f;
        float cfr   =          pr[20] * 0.1f;
        float cwh   =          pr[22] * 0.2f;
        float invfc   = 1.0f / fc;
        float invlpfc = 1.0f / (lp * fc);
        float ncfrcf  = -(cfr * cfmax);
        float omk0    = 1.0f - k0;
        float k0uzl   = k0 * uzl;
        float omk1    = 1.0f - k1;

        float sp = 1e-5f, mw = 1e-5f, sm = 0.5f * fc, suz = 1e-5f, slz = 1e-5f;
        float swc = exp2f(beta * __log2f(sm * invfc));   // sw for step 0
        float qprev = 0.0f;

        auto body = [&](float p, float tc, float pet) {
            // deferred store of previous step's q (operand resolved long ago)
            if (STORE4) { qsim[qoff] = qprev; qoff += GG; }
            // off-chain (forcing-only) terms
            float dt   = tc - tt;
            float msn  = fmaxf(cfmax * dt, 0.0f);
            float mrf  = fmaxf(ncfrcf * dt, 0.0f);
            float rain = (dt >= 0.0f) ? p : 0.0f;
            float snow = p - rain;
            float etk  = fmaf(-invlpfc, pet, 1.0f);
            float omsw = 1.0f - swc;
            // snow / melt-water chains
            float sp1  = sp + snow;
            float melt = fminf(msn, sp1);
            float mw2  = mw + melt;
            float sp2  = sp1 - melt;
            float refr = fminf(mrf, mw2);
            float mw3  = mw2 - refr;
            sp = sp2 + refr;
            float mw4  = fminf(mw3, cwh * sp);
            float tosoil = mw3 - mw4;
            mw = mw4;
            // soil moisture (uses pipelined swc)
            float rt    = rain + tosoil;
            float sm1   = fmaf(rt, omsw, sm);
            float rech  = rt * swc;
            float excess = fmaxf(sm1 - fc, 0.0f);
            float sm2   = fminf(sm1, fc);
            sm = fmaxf(fmaxf(sm2 * etk, sm2 - pet), 1e-5f);
            // issue NEXT step's transcendentals now; latency hides under tail
            swc = exp2f(beta * __log2f(sm * invfc));
            // upper / lower zones
            float suz1 = suz + rech + excess;
            float suz2 = fmaxf(suz1 - perc, 0.0f);
            float pa   = suz1 - suz2;
            float suz3 = fminf(suz2, fmaf(suz2, omk0, k0uzl));
            float suzn = omk1 * suz3;
            float q01  = suz2 - suzn;
            suz = suzn;
            float slz1 = slz + pa;
            float q2   = k2 * slz1;
            slz = slz1 - q2;
            float q = q01 + q2;
            if (STORE4) qprev = q;
            else { atomicAdd(&qsim[qoff], 0.25f * q); qoff += GG; }
        };

        for (int c = 0; c < SS / PD - 1; ++c) {
#pragma unroll
            for (int j = 0; j < PD; ++j) {
                float p = pb[j], tc = tb[j], pet = eb[j];
                pb[j] = x[xoff]; tb[j] = x[xoff + 1]; eb[j] = x[xoff + 2];
                xoff += 3 * GG;
                body(p, tc, pet);
            }
        }
#pragma unroll
        for (int j = 0; j < PD; ++j)                    // peeled last chunk
            body(pb[j], tb[j], eb[j]);
        if (STORE4) qsim[qoff] = qprev;                 // final q[SS-1]
    } else {
        // ---- EXP-HYDRO parameters (descale + derived constants) ----
        const float* pe = pr + 24;
        float f    =           pe[0]  * 0.1f;
        float smax = 100.0f  + pe[2]  * 1400.0f;
        float qmax = 10.0f   + pe[4]  * 40.0f;
        float df   =           pe[6]  * 5.0f;
        float tmax =           pe[8]  * 3.0f;
        float tmin = -3.0f   + pe[10] * 3.0f;
        float invsmax = 1.0f / smax;
        float fl = f * 1.44269504f;              // f * log2(e)
        float c0 = __log2f(qmax) - fl * smax;    // fold qmax into exponent

        float s0 = 1e-5f, s1 = 0.5f * smax;
        float qprev = 0.0f;

        auto body = [&](float p, float tc, float pet) {
            if (STORE4) { qsim[qoff] = qprev; qoff += GG; }
            // off-chain terms
            float mdf = df * fmaxf(tc - tmax, 0.0f);
            float ps  = (tc <= tmin) ? p : 0.0f;
            float prr = p - ps;
            float etk = fmaxf(fmaf(-invsmax, pet, 1.0f), 0.0f);
            // chains
            float mlt = fminf(s0, mdf);
            s0 = fmaxf(s0 - mdf, 0.0f) + ps;
            float s1a = s1 + prr + mlt;
            float qspill = fmaxf(s1a - smax, 0.0f);
            float s1b = fminf(s1a, smax);
            float s1c = s1b * etk;                       // s1b - et (exact)
            float qb  = fminf(exp2f(fmaf(fl, s1c, c0)), s1c);
            s1 = s1c - qb;
            float q = qspill + qb;
            if (STORE4) qprev = q;
            else { atomicAdd(&qsim[qoff], 0.25f * q); qoff += GG; }
        };

        for (int c = 0; c < SS / PD - 1; ++c) {
#pragma unroll
            for (int j = 0; j < PD; ++j) {
                float p = pb[j], tc = tb[j], pet = eb[j];
                pb[j] = x[xoff]; tb[j] = x[xoff + 1]; eb[j] = x[xoff + 2];
                xoff += 3 * GG;
                body(p, tc, pet);
            }
        }
#pragma unroll
        for (int j = 0; j < PD; ++j)
            body(pb[j], tb[j], eb[j]);
        if (STORE4) qsim[qoff] = qprev;
    }
}

// ---------------------------------------------------------------------------
// UH weights: one thread per g, 15 normalized gamma-UH weights once (0.25
// folded). gammaln cancels: w[k] ∝ exp((aa-1)ln(k+.5)-(k+.5)/th).
// ---------------------------------------------------------------------------
__global__ __launch_bounds__(256) void uh_weights(const float* __restrict__ raw,
                                                  float* __restrict__ wbuf) {
    int g = blockIdx.x * 256 + threadIdx.x;
    if (g >= GG) return;
    float a = raw[(size_t)g * 38 + 36] * 2.9f;
    float b = raw[(size_t)g * 38 + 37] * 6.5f;
    float aa = fmaxf(a, 0.0f) + 0.1f;
    float th = fmaxf(b, 0.0f) + 0.5f;
    float am1 = aa - 1.0f;
    float invth = 1.0f / th;

    const float logt[LENF] = {
        -0.69314718f, 0.40546511f, 0.91629073f, 1.25276297f, 1.50407740f,
         1.70474809f, 1.87180218f, 2.01490302f, 2.14006616f, 2.25129180f,
         2.35137526f, 2.44234704f, 2.52572864f, 2.60268969f, 2.67414865f };

    float w[LENF];
    float s = 0.0f;
#pragma unroll
    for (int k = 0; k < LENF; ++k) {
        float tk = (float)k + 0.5f;
        w[k] = expf(am1 * logt[k] - tk * invth);
        s += w[k];
    }
    float scale = 0.25f / s;
#pragma unroll
    for (int k = 0; k < LENF; ++k)
        wbuf[(size_t)k * GG + g] = w[k] * scale;
}

// ---------------------------------------------------------------------------
// Routing kernel, t-tiled: each thread owns one g and TT consecutive t's.
// WPRE: weights preloaded (scale folded). NB=4: slices at stride QS1 with a
// +GG pad-row offset. NB=1 (atomic fallback): single dense slice.
// ---------------------------------------------------------------------------
template<int NB, bool WPRE>
__global__ __launch_bounds__(256) void hydro_route(const float* __restrict__ qsim,
                                                   const float* __restrict__ raw,
                                                   const float* __restrict__ wbuf,
                                                   float* __restrict__ out) {
    int idx = blockIdx.x * 256 + threadIdx.x;
    if (idx >= GG * (SS / TT)) return;
    int g = idx % GG;          // g fast -> coalesced
    int c = idx / GG;
    int t0 = c * TT;

    float w[LENF];
    float scale;
    if (WPRE) {
#pragma unroll
        for (int k = 0; k < LENF; ++k)
            w[k] = wbuf[(size_t)k * GG + g];
        scale = 1.0f;
    } else {
        float a = raw[(size_t)g * 38 + 36] * 2.9f;
        float b = raw[(size_t)g * 38 + 37] * 6.5f;
        float aa = fmaxf(a, 0.0f) + 0.1f;
        float th = fmaxf(b, 0.0f) + 0.5f;
        float am1 = aa - 1.0f;
        float invth = 1.0f / th;
        const float logt[LENF] = {
            -0.69314718f, 0.40546511f, 0.91629073f, 1.25276297f, 1.50407740f,
             1.70474809f, 1.87180218f, 2.01490302f, 2.14006616f, 2.25129180f,
             2.35137526f, 2.44234704f, 2.52572864f, 2.60268969f, 2.67414865f };
        float s = 0.0f;
#pragma unroll
        for (int k = 0; k < LENF; ++k) {
            float tk = (float)k + 0.5f;
            w[k] = expf(am1 * logt[k] - tk * invth);
            s += w[k];
        }
        scale = (NB == 4 ? 0.25f : 1.0f) / s;
    }

    // load qsim[t0-14 .. t0+TT-1] (zeros before t=0), summing NB slices
    float v[TT + LENF - 1];
#pragma unroll
    for (int i = 0; i < TT + LENF - 1; ++i) {
        int tp = t0 - (LENF - 1) + i;
        float sv = 0.0f;
        if (tp >= 0) {
            if (NB == 4) {
                const float* qb = qsim + (size_t)(tp + 1) * GG + g;  // +pad row
                sv = qb[0] + qb[QS1] + qb[2 * QS1] + qb[3 * QS1];
            } else {
                sv = qsim[(size_t)tp * GG + g];
            }
        }
        v[i] = sv;
    }
#pragma unroll
    for (int j = 0; j < TT; ++j) {
        float acc = 0.0f;
#pragma unroll
        for (int k = 0; k < LENF; ++k)
            acc += w[k] * v[j + (LENF - 1) - k];
        out[(size_t)(t0 + j) * GG + g] = (WPRE ? acc : acc * scale);
    }
}

// ---------------------------------------------------------------------------
extern "C" void kernel_launch(void* const* d_in, const int* in_sizes, int n_in,
                              void* d_out, int out_size, void* d_ws, size_t ws_size,
                              hipStream_t stream) {
    const float* x   = (const float*)d_in[0];   // (730, 4000, 3) f32
    const float* raw = (const float*)d_in[1];   // (4000, 38) f32
    float* out  = (float*)d_out;                // (730, 4000) f32
    float* qsim = (float*)d_ws;

    const size_t slices4p = 4 * QS1 * sizeof(float);     // 4 slices + pad rows
    const size_t wbytes   = (size_t)LENF * GG * sizeof(float);
    int rblocks = (GG * (SS / TT) + 255) / 256;
    int sblocks = (4 * GPAD) / 64;

    if (ws_size >= slices4p + wbytes) {
        float* wbuf = qsim + 4 * QS1;
        hydro_scan<true><<<sblocks, 64, 0, stream>>>(x, raw, qsim);
        uh_weights<<<(GG + 255) / 256, 256, 0, stream>>>(raw, wbuf);
        hydro_route<4, true><<<rblocks, 256, 0, stream>>>(qsim, raw, wbuf, out);
    } else {
        hipMemsetAsync(qsim, 0, QN * sizeof(float), stream);
        hydro_scan<false><<<sblocks, 64, 0, stream>>>(x, raw, qsim);
        hydro_route<1, false><<<rblocks, 256, 0, stream>>>(qsim, raw, nullptr, out);
    }
}